// Round 2
// baseline (4829.954 us; speedup 1.0000x reference)
//
#include <hip/hip_runtime.h>
#include <hip/hip_bf16.h>

#define H 1024
#define G4 4096
#define EDIM 256
#define BATCH 64
#define VOUT 32000
#define LDW 1032  // padded LDS stride for Whh slice (2064 B rows)

typedef __attribute__((ext_vector_type(8))) short bh8;
typedef __attribute__((ext_vector_type(4))) float f4;

__device__ __forceinline__ unsigned short f2bf(float f) {
  unsigned u = __float_as_uint(f);
  unsigned r = (u + 0x7fffu + ((u >> 16) & 1u)) >> 16;
  return (unsigned short)r;
}

// async global->LDS, 16 B per lane; LDS dest is wave-uniform base + lane*16
__device__ __forceinline__ void gload16(const void* g, void* l) {
  __builtin_amdgcn_global_load_lds(
      (const __attribute__((address_space(1))) unsigned int*)g,
      (__attribute__((address_space(3))) unsigned int*)l, 16, 0, 0);
}

// ---------------- elementwise helpers ----------------
__global__ void k_cvt(const float* __restrict__ s, unsigned short* __restrict__ d, int n8) {
  int i = blockIdx.x * 256 + threadIdx.x;
  if (i >= n8) return;
  const float4* sp = (const float4*)s;
  float4 a = sp[2 * (size_t)i];
  float4 b = sp[2 * (size_t)i + 1];
  bh8 o;
  o[0] = (short)f2bf(a.x); o[1] = (short)f2bf(a.y);
  o[2] = (short)f2bf(a.z); o[3] = (short)f2bf(a.w);
  o[4] = (short)f2bf(b.x); o[5] = (short)f2bf(b.y);
  o[6] = (short)f2bf(b.z); o[7] = (short)f2bf(b.w);
  *(bh8*)(d + 8 * (size_t)i) = o;
}

__global__ void k_bias(const float* __restrict__ bi, const float* __restrict__ bh,
                       float* __restrict__ out) {
  int i = blockIdx.x * 256 + threadIdx.x;
  out[i] = bi[i] + bh[i];
}

__global__ void k_zero(float4* __restrict__ p, int n4) {
  int i = blockIdx.x * 256 + threadIdx.x;
  if (i < n4) p[i] = make_float4(0.f, 0.f, 0.f, 0.f);
}

__global__ void k_gather(const int* __restrict__ idx, const float* __restrict__ emb,
                         unsigned short* __restrict__ out, int rows) {
  int t = blockIdx.x * 256 + threadIdx.x;
  int r = t >> 5, c8 = (t & 31) * 8;
  if (r >= rows) return;
  const float* e = emb + (size_t)idx[r] * EDIM + c8;
  bh8 o;
#pragma unroll
  for (int j = 0; j < 8; j++) o[j] = (short)f2bf(e[j]);
  *(bh8*)(out + (size_t)r * EDIM + c8) = o;
}

// ---------------- bf16 NT GEMM (m97 structure): C = A@B^T + bias ----------------
// linear LDS [128][64], global_load_lds width 16, 2 barriers/K-step,
// 1-D grid with bijective XCD swizzle, tm-inner for B-tile L2 reuse.
__launch_bounds__(256)
__global__ void k_gemm(const unsigned short* __restrict__ A, const unsigned short* __restrict__ B,
                       float* __restrict__ C, const float* __restrict__ bias,
                       int K, int ldc, int row_off, int m_valid, int grid_m) {
  __shared__ __align__(16) unsigned short As[128 * 64];
  __shared__ __align__(16) unsigned short Bs[128 * 64];
  int nwg = gridDim.x, bid = blockIdx.x;
  int q = nwg >> 3, r = nwg & 7;
  int xcd = bid & 7, sub = bid >> 3;
  int wg = ((xcd < r) ? xcd * (q + 1) : r * (q + 1) + (xcd - r) * q) + sub;
  int tm = wg % grid_m, tn = wg / grid_m;
  int tid = threadIdx.x, lane = tid & 63, wv = tid >> 6;
  int wm = (wv >> 1) << 6, wn = (wv & 1) << 6;
  f4 acc[4][4] = {};
  const size_t a_base = (size_t)tm * 128 * K;
  const size_t b_base = (size_t)tn * 128 * K;
  for (int k0 = 0; k0 < K; k0 += 64) {
#pragma unroll
    for (int i = 0; i < 4; i++) {
      int v = i * 256 + tid;          // 0..1023; lane-contiguous within wave
      int row = v >> 3, ch = (v & 7) * 8;
      int lbase = (v & ~63) * 8;      // wave-uniform LDS elem base
      gload16(A + a_base + (size_t)row * K + k0 + ch, As + lbase);
      gload16(B + b_base + (size_t)row * K + k0 + ch, Bs + lbase);
    }
    __syncthreads();
#pragma unroll
    for (int kk = 0; kk < 2; kk++) {
      int ko = kk * 32 + (lane >> 4) * 8;
      bh8 af[4], bf[4];
#pragma unroll
      for (int x = 0; x < 4; x++) {
        af[x] = *(const bh8*)(As + (wm + x * 16 + (lane & 15)) * 64 + ko);
        bf[x] = *(const bh8*)(Bs + (wn + x * 16 + (lane & 15)) * 64 + ko);
      }
#pragma unroll
      for (int mi = 0; mi < 4; mi++)
#pragma unroll
        for (int ni = 0; ni < 4; ni++)
          acc[mi][ni] = __builtin_amdgcn_mfma_f32_16x16x32_bf16(af[mi], bf[ni], acc[mi][ni], 0, 0, 0);
    }
    __syncthreads();
  }
  int r0 = tm * 128 + wm + (lane >> 4) * 4;
  int c0 = tn * 128 + wn + (lane & 15);
#pragma unroll
  for (int mi = 0; mi < 4; mi++) {
#pragma unroll
    for (int ni = 0; ni < 4; ni++) {
      int col = c0 + ni * 16;
      float bv = bias ? bias[col] : 0.f;
#pragma unroll
      for (int j = 0; j < 4; j++) {
        int row = r0 + mi * 16 + j;
        if (row < m_valid)
          C[(size_t)(row_off + row) * ldc + col] = acc[mi][ni][j] + bv;
      }
    }
  }
}

// ---------------- persistent LSTM phase kernel ----------------
struct PhJob {
  const float* xg;              // [T][64][4096]
  const unsigned short* hinit;  // h input at t=0
  unsigned short* hb0;          // double buffers: input at even t is hb0
  unsigned short* hb1;
  float* c;                     // [64][1024] fp32, continued across phases
  const unsigned short* Whh;    // [4096][1024] bf16
  unsigned short* yout;         // [T][64][1024] or nullptr
  int T;                        // active steps for this job
};
struct PhArgs { PhJob j[2]; unsigned* ctr; int Tmax; };

__global__ void __launch_bounds__(256, 1) k_phase(PhArgs a) {
  __shared__ __align__(16) unsigned short Ws[32 * LDW];  // 66 KB: Whh slice, resident all phase
  __shared__ float Gs[64 * 33];
  const PhJob jb = a.j[blockIdx.x >> 7];
  int wg = blockIdx.x & 127;    // owns h cols [wg*8, wg*8+8)
  int tid = threadIdx.x, lane = tid & 63, wv = tid >> 6;
  unsigned nblk = gridDim.x;

  // stage Whh slice ONCE per phase: local row c in [0,32): global row = (c>>3)*1024 + wg*8 + (c&7)
#pragma unroll
  for (int i = 0; i < 16; i++) {
    int u = i * 256 + tid;
    int row = u >> 7;
    int ch = (u & 127) * 8;
    int grow = ((row >> 3) << 10) + wg * 8 + (row & 7);
    *(bh8*)(Ws + row * LDW + ch) = *(const bh8*)(jb.Whh + (size_t)grow * H + ch);
  }
  __syncthreads();

  const unsigned short* wp0 = Ws + (lane & 15) * LDW + (lane >> 4) * 8;
  const unsigned short* wp1 = wp0 + 16 * LDW;

  for (int t = 0; t < a.Tmax; t++) {
    if (t < jb.T) {
      const unsigned short* hprev = (t == 0) ? jb.hinit : ((t & 1) ? jb.hb1 : jb.hb0);
      unsigned short* hnext = (t & 1) ? jb.hb0 : jb.hb1;
      const float* xg = jb.xg + (size_t)t * (BATCH * G4);

      f4 acc0 = {}, acc1 = {};
      const unsigned short* hp = hprev + (size_t)(wv * 16 + (lane & 15)) * H + (lane >> 4) * 8;
#pragma unroll 8
      for (int kk = 0; kk < 32; kk++) {
        bh8 av = *(const bh8*)(hp + kk * 32);
        bh8 b0 = *(const bh8*)(wp0 + kk * 32);
        bh8 b1 = *(const bh8*)(wp1 + kk * 32);
        acc0 = __builtin_amdgcn_mfma_f32_16x16x32_bf16(av, b0, acc0, 0, 0, 0);
        acc1 = __builtin_amdgcn_mfma_f32_16x16x32_bf16(av, b1, acc1, 0, 0, 0);
      }
#pragma unroll
      for (int j = 0; j < 4; j++) {
        int rr = wv * 16 + (lane >> 4) * 4 + j;
        Gs[rr * 33 + (lane & 15)]      = acc0[j];
        Gs[rr * 33 + 16 + (lane & 15)] = acc1[j];
      }
      __syncthreads();
#pragma unroll
      for (int qq = 0; qq < 2; qq++) {
        int idx = qq * 256 + tid;
        int rr = idx >> 3, hc = idx & 7;
        int gcb = wg * 8 + hc;
        float gi = Gs[rr * 33 + hc]      + xg[(size_t)rr * G4 + gcb];
        float gf = Gs[rr * 33 + 8 + hc]  + xg[(size_t)rr * G4 + 1024 + gcb];
        float gg = Gs[rr * 33 + 16 + hc] + xg[(size_t)rr * G4 + 2048 + gcb];
        float go = Gs[rr * 33 + 24 + hc] + xg[(size_t)rr * G4 + 3072 + gcb];
        float si = 1.f / (1.f + __expf(-gi));
        float sf = 1.f / (1.f + __expf(-gf));
        float so = 1.f / (1.f + __expf(-go));
        float tg = tanhf(gg);
        int ci = rr * H + gcb;
        float cv = sf * jb.c[ci] + si * tg;
        float hv = so * tanhf(cv);
        jb.c[ci] = cv;
        unsigned short hb = f2bf(hv);
        hnext[ci] = hb;
        if (jb.yout) jb.yout[(size_t)t * (BATCH * H) + ci] = hb;
      }
    }
    // grid barrier: monotonic counter, agent-scope release/acquire
    __syncthreads();
    if (tid == 0) {
      __threadfence();
      __hip_atomic_fetch_add(a.ctr, 1u, __ATOMIC_RELEASE, __HIP_MEMORY_SCOPE_AGENT);
      unsigned tgt = (unsigned)(t + 1) * nblk;
      while (__hip_atomic_load(a.ctr, __ATOMIC_ACQUIRE, __HIP_MEMORY_SCOPE_AGENT) < tgt)
        __builtin_amdgcn_s_sleep(2);
      __threadfence();
    }
    __syncthreads();
  }
}

// ---------------- host ----------------
extern "C" void kernel_launch(void* const* d_in, const int* in_sizes, int n_in,
                              void* d_out, int out_size, void* d_ws, size_t ws_size,
                              hipStream_t stream) {
  const int*   src     = (const int*)d_in[0];
  const int*   tgt     = (const int*)d_in[1];
  const float* enc_emb = (const float*)d_in[2];
  const float* dec_emb = (const float*)d_in[3];
  const float* fc_W    = (const float*)d_in[4];
  const float* fc_b    = (const float*)d_in[5];
  const float* eW_ih0  = (const float*)d_in[6];
  const float* eW_hh0  = (const float*)d_in[7];
  const float* eb_ih0  = (const float*)d_in[8];
  const float* eb_hh0  = (const float*)d_in[9];
  const float* eW_ih1  = (const float*)d_in[10];
  const float* eW_hh1  = (const float*)d_in[11];
  const float* eb_ih1  = (const float*)d_in[12];
  const float* eb_hh1  = (const float*)d_in[13];
  const float* dW_ih0  = (const float*)d_in[14];
  const float* dW_hh0  = (const float*)d_in[15];
  const float* db_ih0  = (const float*)d_in[16];
  const float* db_hh0  = (const float*)d_in[17];
  const float* dW_ih1  = (const float*)d_in[18];
  const float* dW_hh1  = (const float*)d_in[19];
  const float* db_ih1  = (const float*)d_in[20];
  const float* db_hh1  = (const float*)d_in[21];

  char* p = (char*)d_ws;
  auto alloc = [&](size_t b) { char* r = p; p += (b + 255) & ~(size_t)255; return r; };

  // zero-arena: [3 barrier ctrs | hbf_e0_0 | hbf_e1_0 | c_e0 | c_e1] = 787200 B
  char* zar = alloc(768 + 131072 * 2 + 262144 * 2);
  unsigned* ctrA = (unsigned*)zar;
  unsigned* ctrB = (unsigned*)(zar + 256);
  unsigned* ctrC = (unsigned*)(zar + 512);
  unsigned short* hbf_e0_0 = (unsigned short*)(zar + 768);
  unsigned short* hbf_e1_0 = (unsigned short*)(zar + 768 + 131072);
  float* c_e0 = (float*)(zar + 768 + 262144);
  float* c_e1 = (float*)(zar + 768 + 524288);
  unsigned short* hbf_e0_1 = (unsigned short*)alloc(131072);
  unsigned short* hbf_e1_1 = (unsigned short*)alloc(131072);
  unsigned short* hbf_d0_0 = (unsigned short*)alloc(131072);
  unsigned short* hbf_d0_1 = (unsigned short*)alloc(131072);
  unsigned short* hbf_d1_0 = (unsigned short*)alloc(131072);
  unsigned short* hbf_d1_1 = (unsigned short*)alloc(131072);

  unsigned short* w_eih0 = (unsigned short*)alloc((size_t)G4 * EDIM * 2);
  unsigned short* w_ehh0 = (unsigned short*)alloc((size_t)G4 * H * 2);
  unsigned short* w_eih1 = (unsigned short*)alloc((size_t)G4 * H * 2);
  unsigned short* w_ehh1 = (unsigned short*)alloc((size_t)G4 * H * 2);
  unsigned short* w_dih0 = (unsigned short*)alloc((size_t)G4 * EDIM * 2);
  unsigned short* w_dhh0 = (unsigned short*)alloc((size_t)G4 * H * 2);
  unsigned short* w_dih1 = (unsigned short*)alloc((size_t)G4 * H * 2);
  unsigned short* w_dhh1 = (unsigned short*)alloc((size_t)G4 * H * 2);
  unsigned short* w_fc   = (unsigned short*)alloc((size_t)VOUT * H * 2);

  unsigned short* xe  = (unsigned short*)alloc((size_t)3072 * EDIM * 2);
  unsigned short* xd  = (unsigned short*)alloc((size_t)3072 * EDIM * 2);
  unsigned short* y0  = (unsigned short*)alloc((size_t)3072 * H * 2);
  unsigned short* d0b = (unsigned short*)alloc((size_t)3072 * H * 2);
  unsigned short* d1b = (unsigned short*)alloc((size_t)3072 * H * 2);
  float* xgA = (float*)alloc((size_t)3072 * G4 * 4);
  float* xgB = (float*)alloc((size_t)3072 * G4 * 4);
  float* bias_e0 = (float*)alloc((size_t)4 * G4 * 4);
  float* bias_e1 = bias_e0 + G4;
  float* bias_d0 = bias_e0 + 2 * G4;
  float* bias_d1 = bias_e0 + 3 * G4;

  auto cvt = [&](const float* s, unsigned short* d, size_t n) {
    int n8 = (int)(n / 8);
    k_cvt<<<dim3((n8 + 255) / 256), dim3(256), 0, stream>>>(s, d, n8);
  };
  cvt(eW_ih0, w_eih0, (size_t)G4 * EDIM);
  cvt(eW_hh0, w_ehh0, (size_t)G4 * H);
  cvt(eW_ih1, w_eih1, (size_t)G4 * H);
  cvt(eW_hh1, w_ehh1, (size_t)G4 * H);
  cvt(dW_ih0, w_dih0, (size_t)G4 * EDIM);
  cvt(dW_hh0, w_dhh0, (size_t)G4 * H);
  cvt(dW_ih1, w_dih1, (size_t)G4 * H);
  cvt(dW_hh1, w_dhh1, (size_t)G4 * H);
  cvt(fc_W,   w_fc,   (size_t)VOUT * H);

  k_bias<<<dim3(16), dim3(256), 0, stream>>>(eb_ih0, eb_hh0, bias_e0);
  k_bias<<<dim3(16), dim3(256), 0, stream>>>(eb_ih1, eb_hh1, bias_e1);
  k_bias<<<dim3(16), dim3(256), 0, stream>>>(db_ih0, db_hh0, bias_d0);
  k_bias<<<dim3(16), dim3(256), 0, stream>>>(db_ih1, db_hh1, bias_d1);

  k_zero<<<dim3(193), dim3(256), 0, stream>>>((float4*)zar, 49200);        // ctrs + states
  k_zero<<<dim3(2000), dim3(256), 0, stream>>>((float4*)d_out, 512000);    // t=0 output block

  k_gather<<<dim3(384), dim3(256), 0, stream>>>(src, enc_emb, xe, 3072);
  k_gather<<<dim3(376), dim3(256), 0, stream>>>(tgt, dec_emb, xd, 3008);

  // input-transform GEMMs
  k_gemm<<<dim3(768), dim3(256), 0, stream>>>(xe, w_eih0, xgA, bias_e0, EDIM, G4, 0, 3072, 24);
  k_gemm<<<dim3(768), dim3(256), 0, stream>>>(xd, w_dih0, xgB, bias_d0, EDIM, G4, 0, 3072, 24);

  // phase A: encoder layer 0, 48 steps
  {
    PhArgs pa{};
    pa.j[0] = PhJob{xgA, hbf_e0_0, hbf_e0_0, hbf_e0_1, c_e0, w_ehh0, y0, 48};
    pa.j[1] = pa.j[0];
    pa.ctr = ctrA; pa.Tmax = 48;
    void* args[] = {&pa};
    hipLaunchCooperativeKernel((const void*)k_phase, dim3(128), dim3(256), args, 0, stream);
  }
  k_gemm<<<dim3(768), dim3(256), 0, stream>>>(y0, w_eih1, xgA, bias_e1, H, G4, 0, 3072, 24);

  // phase B: encoder layer 1 (48) || decoder layer 0 (47)
  {
    PhArgs pa{};
    pa.j[0] = PhJob{xgA, hbf_e1_0, hbf_e1_0, hbf_e1_1, c_e1, w_ehh1, nullptr, 48};
    pa.j[1] = PhJob{xgB, hbf_e0_0, hbf_d0_0, hbf_d0_1, c_e0, w_dhh0, d0b, 47};
    pa.ctr = ctrB; pa.Tmax = 48;
    void* args[] = {&pa};
    hipLaunchCooperativeKernel((const void*)k_phase, dim3(256), dim3(256), args, 0, stream);
  }
  k_gemm<<<dim3(768), dim3(256), 0, stream>>>(d0b, w_dih1, xgB, bias_d1, H, G4, 0, 3072, 24);

  // phase C: decoder layer 1, 47 steps
  {
    PhArgs pa{};
    pa.j[0] = PhJob{xgB, hbf_e1_0, hbf_d1_0, hbf_d1_1, c_e1, w_dhh1, d1b, 47};
    pa.j[1] = pa.j[0];
    pa.ctr = ctrC; pa.Tmax = 47;
    void* args[] = {&pa};
    hipLaunchCooperativeKernel((const void*)k_phase, dim3(128), dim3(256), args, 0, stream);
  }

  // final projection into d_out rows 64..3071 (t=1..47)
  k_gemm<<<dim3(6000), dim3(256), 0, stream>>>(d1b, w_fc, (float*)d_out, fc_b, H, VOUT, 64, 3008, 24);
}

// Round 3
// 2644.358 us; speedup vs baseline: 1.8265x; 1.8265x over previous
//
#include <hip/hip_runtime.h>
#include <hip/hip_bf16.h>

#define H 1024
#define G4 4096
#define EDIM 256
#define BATCH 64
#define VOUT 32000
#define LDW 1032  // padded LDS stride for Whh slice (2064 B rows)

typedef __attribute__((ext_vector_type(8))) short bh8;
typedef __attribute__((ext_vector_type(4))) float f4;

__device__ __forceinline__ unsigned short f2bf(float f) {
  unsigned u = __float_as_uint(f);
  unsigned r = (u + 0x7fffu + ((u >> 16) & 1u)) >> 16;
  return (unsigned short)r;
}

// async global->LDS, 16 B per lane; LDS dest is wave-uniform base + lane*16
__device__ __forceinline__ void gload16(const void* g, void* l) {
  __builtin_amdgcn_global_load_lds(
      (const __attribute__((address_space(1))) unsigned int*)g,
      (__attribute__((address_space(3))) unsigned int*)l, 16, 0, 0);
}

// device-scope (cross-XCD coherent) 16B load: bypasses L1/L2, served by LLC
__device__ __forceinline__ bh8 load_dev(const unsigned short* p) {
  f4 r;
  asm volatile("global_load_dwordx4 %0, %1, off sc1" : "=&v"(r) : "v"(p) : "memory");
  return __builtin_bit_cast(bh8, r);
}
// device-scope 2B store: write-through to LLC
__device__ __forceinline__ void store_dev(unsigned short* p, unsigned short v) {
  unsigned w = v;
  asm volatile("global_store_short %0, %1, off sc1" :: "v"(p), "v"(w) : "memory");
}

// ---------------- elementwise helpers ----------------
__global__ void k_cvt(const float* __restrict__ s, unsigned short* __restrict__ d, int n8) {
  int i = blockIdx.x * 256 + threadIdx.x;
  if (i >= n8) return;
  const float4* sp = (const float4*)s;
  float4 a = sp[2 * (size_t)i];
  float4 b = sp[2 * (size_t)i + 1];
  bh8 o;
  o[0] = (short)f2bf(a.x); o[1] = (short)f2bf(a.y);
  o[2] = (short)f2bf(a.z); o[3] = (short)f2bf(a.w);
  o[4] = (short)f2bf(b.x); o[5] = (short)f2bf(b.y);
  o[6] = (short)f2bf(b.z); o[7] = (short)f2bf(b.w);
  *(bh8*)(d + 8 * (size_t)i) = o;
}

__global__ void k_bias(const float* __restrict__ bi, const float* __restrict__ bh,
                       float* __restrict__ out) {
  int i = blockIdx.x * 256 + threadIdx.x;
  out[i] = bi[i] + bh[i];
}

__global__ void k_zero(float4* __restrict__ p, int n4) {
  int i = blockIdx.x * 256 + threadIdx.x;
  if (i < n4) p[i] = make_float4(0.f, 0.f, 0.f, 0.f);
}

__global__ void k_gather(const int* __restrict__ idx, const float* __restrict__ emb,
                         unsigned short* __restrict__ out, int rows) {
  int t = blockIdx.x * 256 + threadIdx.x;
  int r = t >> 5, c8 = (t & 31) * 8;
  if (r >= rows) return;
  const float* e = emb + (size_t)idx[r] * EDIM + c8;
  bh8 o;
#pragma unroll
  for (int j = 0; j < 8; j++) o[j] = (short)f2bf(e[j]);
  *(bh8*)(out + (size_t)r * EDIM + c8) = o;
}

// ---------------- bf16 NT GEMM (m97 structure): C = A@B^T + bias ----------------
__launch_bounds__(256)
__global__ void k_gemm(const unsigned short* __restrict__ A, const unsigned short* __restrict__ B,
                       float* __restrict__ C, const float* __restrict__ bias,
                       int K, int ldc, int row_off, int m_valid, int grid_m) {
  __shared__ __align__(16) unsigned short As[128 * 64];
  __shared__ __align__(16) unsigned short Bs[128 * 64];
  int nwg = gridDim.x, bid = blockIdx.x;
  int q = nwg >> 3, r = nwg & 7;
  int xcd = bid & 7, sub = bid >> 3;
  int wg = ((xcd < r) ? xcd * (q + 1) : r * (q + 1) + (xcd - r) * q) + sub;
  int tm = wg % grid_m, tn = wg / grid_m;
  int tid = threadIdx.x, lane = tid & 63, wv = tid >> 6;
  int wm = (wv >> 1) << 6, wn = (wv & 1) << 6;
  f4 acc[4][4] = {};
  const size_t a_base = (size_t)tm * 128 * K;
  const size_t b_base = (size_t)tn * 128 * K;
  for (int k0 = 0; k0 < K; k0 += 64) {
#pragma unroll
    for (int i = 0; i < 4; i++) {
      int v = i * 256 + tid;
      int row = v >> 3, ch = (v & 7) * 8;
      int lbase = (v & ~63) * 8;
      gload16(A + a_base + (size_t)row * K + k0 + ch, As + lbase);
      gload16(B + b_base + (size_t)row * K + k0 + ch, Bs + lbase);
    }
    __syncthreads();
#pragma unroll
    for (int kk = 0; kk < 2; kk++) {
      int ko = kk * 32 + (lane >> 4) * 8;
      bh8 af[4], bf[4];
#pragma unroll
      for (int x = 0; x < 4; x++) {
        af[x] = *(const bh8*)(As + (wm + x * 16 + (lane & 15)) * 64 + ko);
        bf[x] = *(const bh8*)(Bs + (wn + x * 16 + (lane & 15)) * 64 + ko);
      }
#pragma unroll
      for (int mi = 0; mi < 4; mi++)
#pragma unroll
        for (int ni = 0; ni < 4; ni++)
          acc[mi][ni] = __builtin_amdgcn_mfma_f32_16x16x32_bf16(af[mi], bf[ni], acc[mi][ni], 0, 0, 0);
    }
    __syncthreads();
  }
  int r0 = tm * 128 + wm + (lane >> 4) * 4;
  int c0 = tn * 128 + wn + (lane & 15);
#pragma unroll
  for (int mi = 0; mi < 4; mi++) {
#pragma unroll
    for (int ni = 0; ni < 4; ni++) {
      int col = c0 + ni * 16;
      float bv = bias ? bias[col] : 0.f;
#pragma unroll
      for (int j = 0; j < 4; j++) {
        int row = r0 + mi * 16 + j;
        if (row < m_valid)
          C[(size_t)(row_off + row) * ldc + col] = acc[mi][ni][j] + bv;
      }
    }
  }
}

// ---------------- persistent LSTM phase kernel ----------------
// Coherence design (per-XCD L2s are NOT coherent):
//  - h buffers: ONLY touched via sc1 (device-scope) ops -> LLC is coherence point.
//  - xg/Whh/bias: read-only during phase -> plain cached.
//  - c, yout: block-private / consumed by later kernels -> plain cached.
//  - barrier: RELAXED atomics only (no acquire/release -> no buffer_wb/inv storms).
struct PhJob {
  const float* xg;              // [T][64][4096]
  const unsigned short* hinit;  // h input at t=0
  unsigned short* hb0;          // h double buffers (final h lands in hb0 for odd last t)
  unsigned short* hb1;
  float* c;                     // [64][1024] fp32, continued across phases
  const unsigned short* Whh;    // [4096][1024] bf16
  unsigned short* yout;         // [T][64][1024] or nullptr
  int T;
};
struct PhArgs { PhJob j[2]; unsigned* ctr; int Tmax; };

__global__ void __launch_bounds__(256, 1) k_phase(PhArgs a) {
  __shared__ __align__(16) unsigned short Ws[32 * LDW];  // Whh slice, resident all phase
  __shared__ float Gs[64 * 33];
  const PhJob jb = a.j[blockIdx.x >> 7];
  int wg = blockIdx.x & 127;    // owns h cols [wg*8, wg*8+8)
  int tid = threadIdx.x, lane = tid & 63, wv = tid >> 6;
  unsigned nblk = gridDim.x;

  // stage Whh slice once per phase (plain loads; read-only data)
#pragma unroll
  for (int i = 0; i < 16; i++) {
    int u = i * 256 + tid;
    int row = u >> 7;
    int ch = (u & 127) * 8;
    int grow = ((row >> 3) << 10) + wg * 8 + (row & 7);
    *(bh8*)(Ws + row * LDW + ch) = *(const bh8*)(jb.Whh + (size_t)grow * H + ch);
  }
  __syncthreads();

  const unsigned short* wp0 = Ws + (lane & 15) * LDW + (lane >> 4) * 8;
  const unsigned short* wp1 = wp0 + 16 * LDW;

  // per-thread pointwise coordinates (q = 0,1)
  // idx = q*256+tid; rr = idx>>3; hc = idx&7; gcb = wg*8+hc
  float xf[8];  // gates i,f,g,o for q=0 then q=1 (current step)
  {
    const float* xg0 = jb.xg;
#pragma unroll
    for (int qq = 0; qq < 2; qq++) {
      int idx = qq * 256 + tid, rr = idx >> 3, gcb = wg * 8 + (idx & 7);
#pragma unroll
      for (int g = 0; g < 4; g++) xf[qq * 4 + g] = xg0[(size_t)rr * G4 + g * 1024 + gcb];
    }
  }

  for (int t = 0; t < a.Tmax; t++) {
    if (t < jb.T) {
      const unsigned short* hprev = (t == 0) ? jb.hinit : ((t & 1) ? jb.hb1 : jb.hb0);
      unsigned short* hnext = (t & 1) ? jb.hb0 : jb.hb1;

      // ---- GEMM: gates64x32 = hprev(64x1024) @ Ws^T, A via sc1 loads ----
      f4 acc0 = {}, acc1 = {};
      const unsigned short* hp = hprev + (size_t)(wv * 16 + (lane & 15)) * H + (lane >> 4) * 8;
      bh8 ab[2][4];
#pragma unroll
      for (int j = 0; j < 4; j++) ab[0][j] = load_dev(hp + j * 32);
#pragma unroll
      for (int g = 0; g < 8; g++) {
        if (g < 7) {
#pragma unroll
          for (int j = 0; j < 4; j++) ab[(g + 1) & 1][j] = load_dev(hp + ((g + 1) * 4 + j) * 32);
        }
        bh8 b0[4], b1[4];
#pragma unroll
        for (int j = 0; j < 4; j++) {
          b0[j] = *(const bh8*)(wp0 + (g * 4 + j) * 32);
          b1[j] = *(const bh8*)(wp1 + (g * 4 + j) * 32);
        }
        if (g < 7) asm volatile("s_waitcnt vmcnt(4)" ::: "memory");
        else       asm volatile("s_waitcnt vmcnt(0)" ::: "memory");
        __builtin_amdgcn_sched_barrier(0);
#pragma unroll
        for (int j = 0; j < 4; j++) {
          acc0 = __builtin_amdgcn_mfma_f32_16x16x32_bf16(ab[g & 1][j], b0[j], acc0, 0, 0, 0);
          acc1 = __builtin_amdgcn_mfma_f32_16x16x32_bf16(ab[g & 1][j], b1[j], acc1, 0, 0, 0);
        }
      }
#pragma unroll
      for (int j = 0; j < 4; j++) {
        int rr = wv * 16 + (lane >> 4) * 4 + j;
        Gs[rr * 33 + (lane & 15)]      = acc0[j];
        Gs[rr * 33 + 16 + (lane & 15)] = acc1[j];
      }
      __syncthreads();

      // ---- pointwise: gates -> c,h ; h stored device-scope ----
#pragma unroll
      for (int qq = 0; qq < 2; qq++) {
        int idx = qq * 256 + tid;
        int rr = idx >> 3, hc = idx & 7;
        int gcb = wg * 8 + hc;
        float gi = Gs[rr * 33 + hc]      + xf[qq * 4 + 0];
        float gf = Gs[rr * 33 + 8 + hc]  + xf[qq * 4 + 1];
        float gg = Gs[rr * 33 + 16 + hc] + xf[qq * 4 + 2];
        float go = Gs[rr * 33 + 24 + hc] + xf[qq * 4 + 3];
        float si = 1.f / (1.f + __expf(-gi));
        float sf = 1.f / (1.f + __expf(-gf));
        float so = 1.f / (1.f + __expf(-go));
        float tg = tanhf(gg);
        int ci = rr * H + gcb;
        float cv = sf * jb.c[ci] + si * tg;
        float hv = so * tanhf(cv);
        jb.c[ci] = cv;
        unsigned short hb = f2bf(hv);
        store_dev(hnext + ci, hb);
        if (jb.yout) jb.yout[(size_t)t * (BATCH * H) + ci] = hb;
      }
    }
    // drain sc1 h-stores to LLC (per-wave), then block-wide sync, then signal
    asm volatile("s_waitcnt vmcnt(0)" ::: "memory");
    __syncthreads();
    if (tid == 0)
      __hip_atomic_fetch_add(a.ctr, 1u, __ATOMIC_RELAXED, __HIP_MEMORY_SCOPE_AGENT);
    // prefetch next step's xg while the barrier resolves (plain loads, not drained)
    if (t + 1 < jb.T) {
      const float* xgn = jb.xg + (size_t)(t + 1) * (BATCH * G4);
#pragma unroll
      for (int qq = 0; qq < 2; qq++) {
        int idx = qq * 256 + tid, rr = idx >> 3, gcb = wg * 8 + (idx & 7);
#pragma unroll
        for (int g = 0; g < 4; g++) xf[qq * 4 + g] = xgn[(size_t)rr * G4 + g * 1024 + gcb];
      }
    }
    if (tid == 0) {
      unsigned tgt = (unsigned)(t + 1) * nblk;
      while (__hip_atomic_load(a.ctr, __ATOMIC_RELAXED, __HIP_MEMORY_SCOPE_AGENT) < tgt)
        __builtin_amdgcn_s_sleep(1);
    }
    __syncthreads();
  }
}

// ---------------- host ----------------
extern "C" void kernel_launch(void* const* d_in, const int* in_sizes, int n_in,
                              void* d_out, int out_size, void* d_ws, size_t ws_size,
                              hipStream_t stream) {
  const int*   src     = (const int*)d_in[0];
  const int*   tgt     = (const int*)d_in[1];
  const float* enc_emb = (const float*)d_in[2];
  const float* dec_emb = (const float*)d_in[3];
  const float* fc_W    = (const float*)d_in[4];
  const float* fc_b    = (const float*)d_in[5];
  const float* eW_ih0  = (const float*)d_in[6];
  const float* eW_hh0  = (const float*)d_in[7];
  const float* eb_ih0  = (const float*)d_in[8];
  const float* eb_hh0  = (const float*)d_in[9];
  const float* eW_ih1  = (const float*)d_in[10];
  const float* eW_hh1  = (const float*)d_in[11];
  const float* eb_ih1  = (const float*)d_in[12];
  const float* eb_hh1  = (const float*)d_in[13];
  const float* dW_ih0  = (const float*)d_in[14];
  const float* dW_hh0  = (const float*)d_in[15];
  const float* db_ih0  = (const float*)d_in[16];
  const float* db_hh0  = (const float*)d_in[17];
  const float* dW_ih1  = (const float*)d_in[18];
  const float* dW_hh1  = (const float*)d_in[19];
  const float* db_ih1  = (const float*)d_in[20];
  const float* db_hh1  = (const float*)d_in[21];

  char* p = (char*)d_ws;
  auto alloc = [&](size_t b) { char* r = p; p += (b + 255) & ~(size_t)255; return r; };

  // zero-arena: [3 barrier ctrs | hbf_e0_0 | hbf_e1_0 | c_e0 | c_e1] = 787200 B
  char* zar = alloc(768 + 131072 * 2 + 262144 * 2);
  unsigned* ctrA = (unsigned*)zar;
  unsigned* ctrB = (unsigned*)(zar + 256);
  unsigned* ctrC = (unsigned*)(zar + 512);
  unsigned short* hbf_e0_0 = (unsigned short*)(zar + 768);
  unsigned short* hbf_e1_0 = (unsigned short*)(zar + 768 + 131072);
  float* c_e0 = (float*)(zar + 768 + 262144);
  float* c_e1 = (float*)(zar + 768 + 524288);
  unsigned short* hbf_e0_1 = (unsigned short*)alloc(131072);
  unsigned short* hbf_e1_1 = (unsigned short*)alloc(131072);
  unsigned short* hbf_d0_0 = (unsigned short*)alloc(131072);
  unsigned short* hbf_d0_1 = (unsigned short*)alloc(131072);
  unsigned short* hbf_d1_0 = (unsigned short*)alloc(131072);
  unsigned short* hbf_d1_1 = (unsigned short*)alloc(131072);

  unsigned short* w_eih0 = (unsigned short*)alloc((size_t)G4 * EDIM * 2);
  unsigned short* w_ehh0 = (unsigned short*)alloc((size_t)G4 * H * 2);
  unsigned short* w_eih1 = (unsigned short*)alloc((size_t)G4 * H * 2);
  unsigned short* w_ehh1 = (unsigned short*)alloc((size_t)G4 * H * 2);
  unsigned short* w_dih0 = (unsigned short*)alloc((size_t)G4 * EDIM * 2);
  unsigned short* w_dhh0 = (unsigned short*)alloc((size_t)G4 * H * 2);
  unsigned short* w_dih1 = (unsigned short*)alloc((size_t)G4 * H * 2);
  unsigned short* w_dhh1 = (unsigned short*)alloc((size_t)G4 * H * 2);
  unsigned short* w_fc   = (unsigned short*)alloc((size_t)VOUT * H * 2);

  unsigned short* xe  = (unsigned short*)alloc((size_t)3072 * EDIM * 2);
  unsigned short* xd  = (unsigned short*)alloc((size_t)3072 * EDIM * 2);
  unsigned short* y0  = (unsigned short*)alloc((size_t)3072 * H * 2);
  unsigned short* d0b = (unsigned short*)alloc((size_t)3072 * H * 2);
  unsigned short* d1b = (unsigned short*)alloc((size_t)3072 * H * 2);
  float* xgA = (float*)alloc((size_t)3072 * G4 * 4);
  float* xgB = (float*)alloc((size_t)3072 * G4 * 4);
  float* bias_e0 = (float*)alloc((size_t)4 * G4 * 4);
  float* bias_e1 = bias_e0 + G4;
  float* bias_d0 = bias_e0 + 2 * G4;
  float* bias_d1 = bias_e0 + 3 * G4;

  auto cvt = [&](const float* s, unsigned short* d, size_t n) {
    int n8 = (int)(n / 8);
    k_cvt<<<dim3((n8 + 255) / 256), dim3(256), 0, stream>>>(s, d, n8);
  };
  cvt(eW_ih0, w_eih0, (size_t)G4 * EDIM);
  cvt(eW_hh0, w_ehh0, (size_t)G4 * H);
  cvt(eW_ih1, w_eih1, (size_t)G4 * H);
  cvt(eW_hh1, w_ehh1, (size_t)G4 * H);
  cvt(dW_ih0, w_dih0, (size_t)G4 * EDIM);
  cvt(dW_hh0, w_dhh0, (size_t)G4 * H);
  cvt(dW_ih1, w_dih1, (size_t)G4 * H);
  cvt(dW_hh1, w_dhh1, (size_t)G4 * H);
  cvt(fc_W,   w_fc,   (size_t)VOUT * H);

  k_bias<<<dim3(16), dim3(256), 0, stream>>>(eb_ih0, eb_hh0, bias_e0);
  k_bias<<<dim3(16), dim3(256), 0, stream>>>(eb_ih1, eb_hh1, bias_e1);
  k_bias<<<dim3(16), dim3(256), 0, stream>>>(db_ih0, db_hh0, bias_d0);
  k_bias<<<dim3(16), dim3(256), 0, stream>>>(db_ih1, db_hh1, bias_d1);

  k_zero<<<dim3(193), dim3(256), 0, stream>>>((float4*)zar, 49200);        // ctrs + states
  k_zero<<<dim3(2000), dim3(256), 0, stream>>>((float4*)d_out, 512000);    // t=0 output block

  k_gather<<<dim3(384), dim3(256), 0, stream>>>(src, enc_emb, xe, 3072);
  k_gather<<<dim3(376), dim3(256), 0, stream>>>(tgt, dec_emb, xd, 3008);

  // input-transform GEMMs
  k_gemm<<<dim3(768), dim3(256), 0, stream>>>(xe, w_eih0, xgA, bias_e0, EDIM, G4, 0, 3072, 24);
  k_gemm<<<dim3(768), dim3(256), 0, stream>>>(xd, w_dih0, xgB, bias_d0, EDIM, G4, 0, 3072, 24);

  // phase A: encoder layer 0, 48 steps
  {
    PhArgs pa{};
    pa.j[0] = PhJob{xgA, hbf_e0_0, hbf_e0_0, hbf_e0_1, c_e0, w_ehh0, y0, 48};
    pa.j[1] = pa.j[0];
    pa.ctr = ctrA; pa.Tmax = 48;
    void* args[] = {&pa};
    hipLaunchCooperativeKernel((const void*)k_phase, dim3(128), dim3(256), args, 0, stream);
  }
  k_gemm<<<dim3(768), dim3(256), 0, stream>>>(y0, w_eih1, xgA, bias_e1, H, G4, 0, 3072, 24);

  // phase B: encoder layer 1 (48) || decoder layer 0 (47)
  {
    PhArgs pa{};
    pa.j[0] = PhJob{xgA, hbf_e1_0, hbf_e1_0, hbf_e1_1, c_e1, w_ehh1, nullptr, 48};
    pa.j[1] = PhJob{xgB, hbf_e0_0, hbf_d0_0, hbf_d0_1, c_e0, w_dhh0, d0b, 47};
    pa.ctr = ctrB; pa.Tmax = 48;
    void* args[] = {&pa};
    hipLaunchCooperativeKernel((const void*)k_phase, dim3(256), dim3(256), args, 0, stream);
  }
  k_gemm<<<dim3(768), dim3(256), 0, stream>>>(d0b, w_dih1, xgB, bias_d1, H, G4, 0, 3072, 24);

  // phase C: decoder layer 1, 47 steps
  {
    PhArgs pa{};
    pa.j[0] = PhJob{xgB, hbf_e1_0, hbf_d1_0, hbf_d1_1, c_e1, w_dhh1, d1b, 47};
    pa.j[1] = pa.j[0];
    pa.ctr = ctrC; pa.Tmax = 47;
    void* args[] = {&pa};
    hipLaunchCooperativeKernel((const void*)k_phase, dim3(128), dim3(256), args, 0, stream);
  }

  // final projection into d_out rows 64..3071 (t=1..47)
  k_gemm<<<dim3(6000), dim3(256), 0, stream>>>(d1b, w_fc, (float*)d_out, fc_b, H, VOUT, 64, 3008, 24);
}